// Round 1
// 252.426 us; speedup vs baseline: 1.0442x; 1.0442x over previous
//
#include <hip/hip_runtime.h>

// Two-kernel, atomic-free formulation.
//
// Kernel 1: grid (B, nchunk). Block (row, c) covers columns
//   [c*1024, c*1024+1023] of row `row` — exactly one float4 per thread
//   (256 threads * 4). Blocks whose window starts past idx exit
//   immediately (load balancing at 1024-elem granularity instead of
//   8192). Each block writes ONE float partial to ws[row*nchunk + c]
//   (plain store, slot written by exactly one block -> no memset, no
//   atomics, no same-address serialization).
//
// Kernel 2: single block, 1024 threads: s_row = sum of nchunk partials,
//   out = sum(s_row^2) / B. Writes out directly -> the out-memset node
//   is gone (d_out poison is overwritten unconditionally).
//
// Per-element coefficient of (y_pred-y_true), as before:
//   coeff(k) = 0.5 * ( (x[k]-x[k-1]) * [1 <= k <= idx]
//                    + (x[k+1]-x[k]) * [k < idx] )

#define CHUNK 1024  // 256 threads * float4

__global__ __launch_bounds__(256) void strain_partial_kernel(
    const float* __restrict__ y_pred,
    const float* __restrict__ y_true,
    const float* __restrict__ x,
    const int*   __restrict__ fidx,
    float* __restrict__ ws,
    int n)
{
    const int row    = blockIdx.x;
    const int chunk  = blockIdx.y;
    const int nchunk = gridDim.y;
    const int tid    = threadIdx.x;

    int idx = fidx[row];
    idx = idx < 0 ? 0 : (idx > n - 1 ? n - 1 : idx);

    const int base = chunk * CHUNK;
    const long long slot = (long long)row * nchunk + chunk;

    if (base > idx) {                 // block-uniform: whole window masked
        if (tid == 0) ws[slot] = 0.0f;
        return;
    }

    float acc = 0.0f;
    const int k0 = base + tid * 4;
    if (k0 <= idx) {
        const float* p = y_pred + (long long)row * n;
        const float* t = y_true + (long long)row * n;
        float4 pv = *(const float4*)(p + k0);
        float4 tv = *(const float4*)(t + k0);
        float4 xv = *(const float4*)(x + k0);
        float xm = (k0 >= 1)    ? x[k0 - 1] : xv.x;   // value unused when k0==0
        float xp = (k0 + 4 < n) ? x[k0 + 4] : xv.w;   // value unused when masked
        float xs[6] = {xm, xv.x, xv.y, xv.z, xv.w, xp};
        float dv[4] = {pv.x - tv.x, pv.y - tv.y, pv.z - tv.z, pv.w - tv.w};
        #pragma unroll
        for (int e = 0; e < 4; ++e) {
            int k = k0 + e;
            float left  = (k >= 1 && k <= idx) ? (xs[e + 1] - xs[e])     : 0.0f;
            float right = (k < idx)            ? (xs[e + 2] - xs[e + 1]) : 0.0f;
            acc += 0.5f * (left + right) * dv[e];
        }
    }

    // wave (64-lane) shuffle reduction, then cross-wave via LDS
    #pragma unroll
    for (int off = 32; off > 0; off >>= 1)
        acc += __shfl_down(acc, off, 64);

    __shared__ float wave_sums[4];
    if ((tid & 63) == 0) wave_sums[tid >> 6] = acc;
    __syncthreads();

    if (tid == 0)
        ws[slot] = wave_sums[0] + wave_sums[1] + wave_sums[2] + wave_sums[3];
}

__global__ __launch_bounds__(1024) void strain_finalize_kernel(
    const float* __restrict__ ws,
    float* __restrict__ out,
    int b, int nchunk, float inv_b)
{
    const int tid = threadIdx.x;
    float acc = 0.0f;

    if ((nchunk & 3) == 0) {
        for (int r = tid; r < b; r += 1024) {
            const float4* w = (const float4*)(ws + (long long)r * nchunk);
            float s = 0.0f;
            for (int c = 0; c < (nchunk >> 2); ++c) {
                float4 v = w[c];
                s += (v.x + v.y) + (v.z + v.w);
            }
            acc += s * s;
        }
    } else {
        for (int r = tid; r < b; r += 1024) {
            float s = 0.0f;
            for (int c = 0; c < nchunk; ++c)
                s += ws[(long long)r * nchunk + c];
            acc += s * s;
        }
    }

    #pragma unroll
    for (int off = 32; off > 0; off >>= 1)
        acc += __shfl_down(acc, off, 64);

    __shared__ float wave_sums[16];
    if ((tid & 63) == 0) wave_sums[tid >> 6] = acc;
    __syncthreads();

    if (tid == 0) {
        float s = 0.0f;
        #pragma unroll
        for (int w = 0; w < 16; ++w) s += wave_sums[w];
        out[0] = s * inv_b;   // unconditional write: overwrites 0xAA poison
    }
}

extern "C" void kernel_launch(void* const* d_in, const int* in_sizes, int n_in,
                              void* d_out, int out_size, void* d_ws, size_t ws_size,
                              hipStream_t stream) {
    const float* y_pred = (const float*)d_in[0];
    const float* y_true = (const float*)d_in[1];
    const float* x      = (const float*)d_in[2];
    const int*   fidx   = (const int*)d_in[3];
    float* out = (float*)d_out;
    float* ws  = (float*)d_ws;   // needs b*nchunk*4 B = 128 KB for 4096x8192

    const int n = in_sizes[2];   // 8192
    const int b = in_sizes[3];   // 4096
    const int nchunk = (n + CHUNK - 1) / CHUNK;   // 8

    strain_partial_kernel<<<dim3(b, nchunk), dim3(256), 0, stream>>>(
        y_pred, y_true, x, fidx, ws, n);
    strain_finalize_kernel<<<dim3(1), dim3(1024), 0, stream>>>(
        ws, out, b, nchunk, 1.0f / (float)b);
}